// Round 18
// baseline (76.999 us; speedup 1.0000x reference)
//
#include <hip/hip_runtime.h>
#include <stddef.h>

namespace {
constexpr int Hc = 256, Wc = 256, Cc = 64, Bc = 4, Dc = 81;
constexpr int CH = Hc * Wc;  // channel stride in floats
}

#define PIN() asm volatile("" ::: "memory")
#define VMW(N) asm volatile("s_waitcnt vmcnt(" #N ")" ::: "memory")

// whole-wave lane shifts (DPP). bound_ctrl=1 -> edge lanes read 0 == zero-pad
#define DPPL(x) __builtin_amdgcn_update_dpp(0, (x), 0x138, 0xf, 0xf, true)
#define DPPR(x) __builtin_amdgcn_update_dpp(0, (x), 0x130, 0xf, 0xf, true)

// clang's AMDGPU builtins use __fp16 vectors (type letter 'h'), NOT _Float16
typedef __fp16 half2v __attribute__((ext_vector_type(2)));

// pack two f32 (channel pair) into v2f16, as int for DPP transport
static __device__ __forceinline__ int pk2(float a, float b) {
#if __has_builtin(__builtin_amdgcn_cvt_pkrtz)
    half2v h = __builtin_amdgcn_cvt_pkrtz(a, b);
#else
    half2v h; h.x = (__fp16)a; h.y = (__fp16)b;
#endif
    return __builtin_bit_cast(int, h);
}

// f32 += dot2(v2f16, v2f16) -- V_DOT2_F32_F16
static __device__ __forceinline__ float dot2f(int q, int w, float c) {
#if __has_builtin(__builtin_amdgcn_fdot2)
    return __builtin_amdgcn_fdot2(__builtin_bit_cast(half2v, q),
                                  __builtin_bit_cast(half2v, w), c, false);
#else
    half2v a = __builtin_bit_cast(half2v, q);
    half2v b = __builtin_bit_cast(half2v, w);
    return c + (float)a.x * (float)b.x + (float)a.y * (float)b.y;
#endif
}

// One CHANNEL-PAIR step: pack x2 quads (A0=ch even, A1=ch odd), DPP builds
// the packed 12-wide window; x1 comes PRE-PACKED from LDS (int4 XI).
// acc[jj][s] += x1[pair][4t+s] . x2[pair][4t+s-jj+4]
#define FMP(A0, A1, XI)                                                     \
    do {                                                                    \
        const int P0_ = pk2(A0.x, A1.x), P1_ = pk2(A0.y, A1.y);             \
        const int P2_ = pk2(A0.z, A1.z), P3_ = pk2(A0.w, A1.w);             \
        const int w_[12] = {DPPL(P0_), DPPL(P1_), DPPL(P2_), DPPL(P3_),     \
                            P0_,       P1_,       P2_,       P3_,           \
                            DPPR(P0_), DPPR(P1_), DPPR(P2_), DPPR(P3_)};    \
        const int q_[4] = {XI.x, XI.y, XI.z, XI.w};                         \
        _Pragma("unroll") for (int jj = 0; jj < 9; ++jj)                    \
            _Pragma("unroll") for (int s = 0; s < 4; ++s)                   \
                acc[jj][s] = dot2f(q_[s], w_[s - jj + 8], acc[jj][s]);      \
    } while (0)

#define ISX(T, OFF)                                                         \
    do {                                                                    \
        xq##T = *(const float4*)(x2p + (size_t)(OFF) * CH);                 \
        PIN();                                                              \
    } while (0)

// read packed x1 pair IDX from LDS (one ds_read_b128)
#define RX1(X, IDX) X = *(const int4*)&xp[(IDX) * 256 + 4 * t]

// Block = 9 waves = one output row (b,h). Wave wi: offset i=wi-4, x2 row
// r=h+4-wi (clamped; invalid waves zero acc post-loop). Lane t: pixels
// 4t..4t+3. BARRIER-FREE main loop: x1 is pre-packed f16x2 (channel pairs)
// into a 32 KB LDS slab once (one barrier), then each pair-step is just
// 1 ds_read_b128 + 2 x2 quad loads + 4 pk2 + 8 DPP + 36 v_dot2.
// 8 x2 stage quads -> 8-channel lookahead, uniform VMW(6) ladder.
// [R13 config -- measured best 70.5 us; R14-R17 variants all regressed.]
__global__ __launch_bounds__(576)
void corr_softmax_kernel(const float* __restrict__ x1,
                         const float* __restrict__ x2,
                         float* __restrict__ out)
{
    __shared__ __align__(16) int xp[32 * 256];  // packed x1 [pair][px], 32 KB

    const int tid = threadIdx.x;
    const int wi  = tid >> 6;   // 0..8
    const int t   = tid & 63;
    // XCD-aware swizzle (kept since R2: FETCH 294->~72 MB)
    const int bid = blockIdx.x;
    const int bh  = (bid & 7) * 128 + (bid >> 3);
    const int b   = bh >> 8;
    const int h   = bh & 255;

    // ---- cooperative x1 pre-pack: 32 pairs x 64 px-quads = 2048 tasks ----
    const float* x1row = x1 + (size_t)b * Cc * CH + (size_t)h * Wc;
#pragma unroll
    for (int kk = 0; kk < 4; ++kk) {
        const int T = tid + 576 * kk;
        if (T < 2048) {
            const int e = T >> 6, p = T & 63;
            float4 a0 = *(const float4*)(x1row + (size_t)(2 * e) * CH + 4 * p);
            float4 a1 = *(const float4*)(x1row + (size_t)(2 * e + 1) * CH + 4 * p);
            int4 w;
            w.x = pk2(a0.x, a1.x); w.y = pk2(a0.y, a1.y);
            w.z = pk2(a0.z, a1.z); w.w = pk2(a0.w, a1.w);
            *(int4*)&xp[e * 256 + 4 * p] = w;
        }
    }
    __syncthreads();  // drains staging vmcnt too -- queue starts clean

    float acc[9][4];
#pragma unroll
    for (int jj = 0; jj < 9; ++jj)
#pragma unroll
        for (int s = 0; s < 4; ++s)
            acc[jj][s] = 0.f;

    const int r  = h + 4 - wi;                           // x2 row = h - i
    const int rr = (r < 0) ? 0 : ((r > 255) ? 255 : r);  // clamped, uniform path

    const float* x2p = x2 + (size_t)b * Cc * CH + (size_t)rr * Wc + 4 * t;

    float4 xq0, xq1, xq2, xq3, xq4, xq5, xq6, xq7;  // x2 stages (8 channels)
    int4 xa, xb;                                    // packed x1 cur/next

    // prologue: prime x2 stages with channels 0..7; x1 pair 0
    ISX(0, 0); ISX(1, 1); ISX(2, 2); ISX(3, 3);
    ISX(4, 4); ISX(5, 5); ISX(6, 6); ISX(7, 7);
    RX1(xa, 0);

#pragma unroll 1
    for (int g = 0; g < 7; ++g) {   // steady: pairs 4g..4g+3, issue ch +8..+15
        const int e1 = 4 * g;
        VMW(6); RX1(xb, e1 + 1); FMP(xq0, xq1, xa); ISX(0, 8);  ISX(1, 9);
        VMW(6); RX1(xa, e1 + 2); FMP(xq2, xq3, xb); ISX(2, 10); ISX(3, 11);
        VMW(6); RX1(xb, e1 + 3); FMP(xq4, xq5, xa); ISX(4, 12); ISX(5, 13);
        VMW(6); RX1(xa, e1 + 4); FMP(xq6, xq7, xb); ISX(6, 14); ISX(7, 15);
        x2p += (size_t)8 * CH;
    }
    // drain: pairs 28..31
    VMW(6); RX1(xb, 29); FMP(xq0, xq1, xa);
    VMW(4); RX1(xa, 30); FMP(xq2, xq3, xb);
    VMW(2); RX1(xb, 31); FMP(xq4, xq5, xa);
    VMW(0); FMP(xq6, xq7, xb);

    // invalid x2 rows (out of [0,256)) correlate to zero: wipe their acc
    if ((unsigned)r >= (unsigned)Hc) {
#pragma unroll
        for (int jj = 0; jj < 9; ++jj)
#pragma unroll
            for (int s = 0; s < 4; ++s)
                acc[jj][s] = 0.f;
    }

    __syncthreads();  // x1 slab dead; alias the reduction buffer onto it
    float* red = (float*)xp;

    // ---- softmax over 81 channels, reduced across the 9 waves ----
    float m0, m1, m2, m3;
    {
        float v0 = acc[0][0], v1 = acc[0][1], v2 = acc[0][2], v3 = acc[0][3];
#pragma unroll
        for (int jj = 1; jj < 9; ++jj) {
            v0 = fmaxf(v0, acc[jj][0]);
            v1 = fmaxf(v1, acc[jj][1]);
            v2 = fmaxf(v2, acc[jj][2]);
            v3 = fmaxf(v3, acc[jj][3]);
        }
        m0 = v0; m1 = v1; m2 = v2; m3 = v3;
    }
    *(float4*)(red + wi * 256 + 4 * t) = make_float4(m0, m1, m2, m3);
    __syncthreads();

    float M0, M1, M2, M3;
    {
        float4 q = *(const float4*)(red + 4 * t);
        M0 = q.x; M1 = q.y; M2 = q.z; M3 = q.w;
#pragma unroll
        for (int w2 = 1; w2 < 9; ++w2) {
            float4 qq = *(const float4*)(red + w2 * 256 + 4 * t);
            M0 = fmaxf(M0, qq.x); M1 = fmaxf(M1, qq.y);
            M2 = fmaxf(M2, qq.z); M3 = fmaxf(M3, qq.w);
        }
    }

    float s0 = 0.f, s1 = 0.f, s2 = 0.f, s3 = 0.f;
#pragma unroll
    for (int jj = 0; jj < 9; ++jj) {
        acc[jj][0] = __expf(acc[jj][0] - M0); s0 += acc[jj][0];
        acc[jj][1] = __expf(acc[jj][1] - M1); s1 += acc[jj][1];
        acc[jj][2] = __expf(acc[jj][2] - M2); s2 += acc[jj][2];
        acc[jj][3] = __expf(acc[jj][3] - M3); s3 += acc[jj][3];
    }
    __syncthreads();  // everyone done reading maxes
    *(float4*)(red + wi * 256 + 4 * t) = make_float4(s0, s1, s2, s3);
    __syncthreads();

    float S0, S1, S2, S3;
    {
        float4 q = *(const float4*)(red + 4 * t);
        S0 = q.x; S1 = q.y; S2 = q.z; S3 = q.w;
#pragma unroll
        for (int w2 = 1; w2 < 9; ++w2) {
            float4 qq = *(const float4*)(red + w2 * 256 + 4 * t);
            S0 += qq.x; S1 += qq.y; S2 += qq.z; S3 += qq.w;
        }
    }
    const float i0 = 1.0f / S0, i1 = 1.0f / S1, i2 = 1.0f / S2, i3 = 1.0f / S3;

    // k = (9*(wi-4) + (jj-4)) mod 81 = 9*wi + jj + 41 (mod 81)
    float* outp = out + (size_t)b * Dc * CH + (size_t)h * Wc + 4 * t;
#pragma unroll
    for (int jj = 0; jj < 9; ++jj) {
        int kc = 9 * wi + jj + 41;
        if (kc >= 81) kc -= 81;
        float4 o = make_float4(acc[jj][0] * i0, acc[jj][1] * i1,
                               acc[jj][2] * i2, acc[jj][3] * i3);
        *(float4*)(outp + (size_t)kc * CH) = o;
    }
}

extern "C" void kernel_launch(void* const* d_in, const int* in_sizes, int n_in,
                              void* d_out, int out_size, void* d_ws, size_t ws_size,
                              hipStream_t stream) {
    (void)in_sizes; (void)n_in; (void)d_ws; (void)ws_size; (void)out_size;
    const float* x1 = (const float*)d_in[0];
    const float* x2 = (const float*)d_in[1];
    float* out = (float*)d_out;
    dim3 grid(Bc * Hc);   // 1024 blocks: one per (b, h) row
    dim3 block(576);      // 9 waves
    hipLaunchKernelGGL(corr_softmax_kernel, grid, block, 0, stream, x1, x2, out);
}